// Round 4
// baseline (116.375 us; speedup 1.0000x reference)
//
#include <hip/hip_runtime.h>
#include <math.h>

#define NB 16
#define NS 4096
#define ND 1024
#define NH 16
#define LUTN 4096
#define TS 32        // s-rows per block in k_scores
#define NCHUNK 128   // s-chunks in k_ctx
#define SLABB 8      // batches per slab (2 slabs: 128 MiB each, fits 256 MiB L3)

#define KF   651.8986469044033f      // LUT_SIZE / (2*pi)
#define PHIF 1.6180339887498949f
#define ANGF 0.0015339807878856412f  // 2*pi / LUT_SIZE
#define INV_SCALE (1.0f / 11.313708498984761f)  // 1/sqrt(2*dh)

// workspace layout, in floats
#define OFF_E     0          // exp(scores) [NB][NH][NS] = 1048576 floats
#define OFF_INVZ  1048576    // 256: 1/sum per (b,h)
#define OFF_WSUM  1048832    // 65536: per-(b,s) collapsed weight
#define OFF_PART  1114368    // [NCHUNK][NB][ND] = 2097152 context partials

__global__ __launch_bounds__(256) void k_scores(const float* __restrict__ cached,
                                                const float* __restrict__ x,
                                                const float* __restrict__ t,
                                                const float* __restrict__ wq,
                                                const float* __restrict__ bq,
                                                const float* __restrict__ wk,
                                                const float* __restrict__ bk,
                                                float* __restrict__ ws,
                                                int b0) {
    __shared__ float ssc[NH * TS];     // 2 KiB transpose buffer
    int tid = threadIdx.x;
    int bid = blockIdx.x;
    int b = b0 + bid / (NS / TS);
    int s0 = (bid % (NS / TS)) * TS;
    int m = tid * 4;

    // key params with LUT scale folded in: idx = rint(v*krK + kbK)
    float4 wkv = *(const float4*)(wk + m);
    float4 kbv = *(const float4*)(bk + m);
    float4 krK, kbK;
    krK.x = KF / (1.0f + fabsf(wkv.x));
    krK.y = KF / (1.0f + fabsf(wkv.y));
    krK.z = KF / (1.0f + fabsf(wkv.z));
    krK.w = KF / (1.0f + fabsf(wkv.w));
    kbK.x = kbv.x * KF;
    kbK.y = kbv.y * KF;
    kbK.z = kbv.z * KF;
    kbK.w = kbv.w * KF;

    // quantized query phase (in radians, pre-negated): jqA = -round(thq*K)*ANGF
    float tphi = t[b] * PHIF;
    float4 xv = *(const float4*)(x + b * ND + m);
    float4 wqv = *(const float4*)(wq + m);
    float4 bqv = *(const float4*)(bq + m);
    float jq0 = -rintf((xv.x / (1.0f + fabsf(wqv.x)) + bqv.x + tphi) * KF) * ANGF;
    float jq1 = -rintf((xv.y / (1.0f + fabsf(wqv.y)) + bqv.y + tphi) * KF) * ANGF;
    float jq2 = -rintf((xv.z / (1.0f + fabsf(wqv.z)) + bqv.z + tphi) * KF) * ANGF;
    float jq3 = -rintf((xv.w / (1.0f + fabsf(wqv.w)) + bqv.w + tphi) * KF) * ANGF;

    const float* base = cached + ((size_t)b * NS + s0) * ND + m;
    #pragma unroll 4
    for (int si = 0; si < TS; ++si) {
        float4 v = *(const float4*)(base + (size_t)si * ND);
        // cos(theta_k_hat - theta_q_hat) == cos_k*cos_q + sin_k*sin_q exactly
        float a0 = fmaf(rintf(fmaf(v.x, krK.x, kbK.x)), ANGF, jq0);
        float a1 = fmaf(rintf(fmaf(v.y, krK.y, kbK.y)), ANGF, jq1);
        float a2 = fmaf(rintf(fmaf(v.z, krK.z, kbK.z)), ANGF, jq2);
        float a3 = fmaf(rintf(fmaf(v.w, krK.w, kbK.w)), ANGF, jq3);
        float p = (__cosf(a0) + __cosf(a1)) + (__cosf(a2) + __cosf(a3));
        // reduce over the 16 lanes covering one head
        p += __shfl_xor(p, 1, 16);
        p += __shfl_xor(p, 2, 16);
        p += __shfl_xor(p, 4, 16);
        p += __shfl_xor(p, 8, 16);
        if ((tid & 15) == 0) ssc[(tid >> 4) * TS + si] = p * INV_SCALE;
    }
    __syncthreads();
    // coalesced exp(score) write: 512 values, 2 per thread
    int i0 = tid * 2;
    int h = i0 >> 5;          // /TS
    int sl = i0 & 31;
    float2 ev;
    ev.x = __expf(ssc[i0]);
    ev.y = __expf(ssc[i0 + 1]);
    *(float2*)(ws + OFF_E + ((size_t)(b * NH + h)) * NS + s0 + sl) = ev;
}

__global__ __launch_bounds__(256) void k_zsum(float* __restrict__ ws, int row0) {
    int row = row0 + blockIdx.x;
    int tid = threadIdx.x;
    const float4* sr = (const float4*)(ws + OFF_E + (size_t)row * NS);
    float sum = 0.f;
    #pragma unroll
    for (int j = 0; j < 4; ++j) {
        float4 r = sr[tid + j * 256];
        sum += (r.x + r.y) + (r.z + r.w);
    }
    #pragma unroll
    for (int off = 32; off > 0; off >>= 1) sum += __shfl_xor(sum, off);
    __shared__ float reds[4];
    int wv = tid >> 6, ln = tid & 63;
    if (ln == 0) reds[wv] = sum;
    __syncthreads();
    if (tid == 0)
        ws[OFF_INVZ + row] = 1.0f / ((reds[0] + reds[1]) + (reds[2] + reds[3]));
}

__global__ __launch_bounds__(256) void k_wsum(float* __restrict__ ws, int b0) {
    int gid = b0 * NS + blockIdx.x * 256 + threadIdx.x;
    int b = gid >> 12;
    int s = gid & 4095;
    float acc = 0.f;
    #pragma unroll
    for (int h = 0; h < NH; ++h) {
        int row = b * NH + h;
        acc = fmaf(ws[OFF_E + (size_t)row * NS + s], ws[OFF_INVZ + row], acc);
    }
    ws[OFF_WSUM + gid] = acc;
}

__global__ __launch_bounds__(256) void k_ctx(const float* __restrict__ cached,
                                             float* __restrict__ ws, int b0) {
    int bid = blockIdx.x;             // SLABB*NCHUNK
    int b = b0 + bid / NCHUNK, c = bid % NCHUNK;
    int s0 = c * (NS / NCHUNK);
    int tid = threadIdx.x;
    const float* base = cached + ((size_t)b * NS + s0) * ND + tid * 4;
    const float* wp = ws + OFF_WSUM + b * NS + s0;
    float4 acc = {0.f, 0.f, 0.f, 0.f};
    #pragma unroll 8
    for (int si = 0; si < NS / NCHUNK; ++si) {
        float w = wp[si];
        float4 v = *(const float4*)(base + (size_t)si * ND);
        acc.x = fmaf(w, v.x, acc.x);
        acc.y = fmaf(w, v.y, acc.y);
        acc.z = fmaf(w, v.z, acc.z);
        acc.w = fmaf(w, v.w, acc.w);
    }
    *(float4*)(ws + OFF_PART + ((size_t)c * NB + b) * ND + tid * 4) = acc;
}

__global__ __launch_bounds__(256) void k_out(const float* __restrict__ t,
                                             const float* __restrict__ wo,
                                             const float* __restrict__ bo,
                                             const float* __restrict__ osc,
                                             const float* __restrict__ ws,
                                             float* __restrict__ out) {
    int gid = blockIdx.x * 256 + threadIdx.x;  // NB*ND
    int b = gid >> 10, m = gid & 1023;
    float acc = 0.f;
    const float* part = ws + OFF_PART;
    #pragma unroll 8
    for (int c = 0; c < NCHUNK; ++c)
        acc += part[((size_t)c * NB + b) * ND + m];
    float theta = acc / (1.0f + fabsf(wo[m])) + bo[m] + t[b] * PHIF;
    int idx = ((int)rintf(theta * KF)) & (LUTN - 1);
    float ang = (float)idx * ANGF;
    // precise libm trig: bit-matches the np table entries
    out[gid] = osc[m] * (cosf(ang) + sinf(ang));
}

extern "C" void kernel_launch(void* const* d_in, const int* in_sizes, int n_in,
                              void* d_out, int out_size, void* d_ws, size_t ws_size,
                              hipStream_t stream) {
    const float* x      = (const float*)d_in[0];
    const float* cached = (const float*)d_in[1];
    const float* t      = (const float*)d_in[2];
    const float* wq     = (const float*)d_in[3];
    const float* bq     = (const float*)d_in[4];
    const float* wk     = (const float*)d_in[5];
    const float* bk     = (const float*)d_in[6];
    const float* wo     = (const float*)d_in[7];
    const float* bo     = (const float*)d_in[8];
    const float* osc    = (const float*)d_in[9];
    float* ws  = (float*)d_ws;
    float* out = (float*)d_out;

    // slab-wise: scores pass pulls 128 MiB of cached into L3; ctx re-reads it
    // before the next slab's stream evicts it. Stream-ordered => G16-safe.
    for (int slab = 0; slab < NB / SLABB; ++slab) {
        int b0 = slab * SLABB;
        k_scores<<<SLABB * (NS / TS), 256, 0, stream>>>(cached, x, t, wq, bq, wk, bk, ws, b0);
        k_zsum<<<SLABB * NH, 256, 0, stream>>>(ws, b0 * NH);
        k_wsum<<<SLABB * NS / 256, 256, 0, stream>>>(ws, b0);
        k_ctx<<<SLABB * NCHUNK, 256, 0, stream>>>(cached, ws, b0);
    }
    k_out<<<NB * ND / 256, 256, 0, stream>>>(t, wo, bo, osc, ws, out);
}

// Round 5
// 99.914 us; speedup vs baseline: 1.1648x; 1.1648x over previous
//
#include <hip/hip_runtime.h>
#include <math.h>

#define NB 16
#define NS 4096
#define ND 1024
#define NH 16
#define LUTN 4096
#define NC 32            // s-chunks (grid = NB*NC = 512 blocks, 2/CU)
#define SC (NS / NC)     // 128 rows per block
#define RG 8             // rows per group (LDS broadcast granularity)

#define KF   651.8986469044033f      // LUT_SIZE / (2*pi)
#define PHIF 1.6180339887498949f
#define ANGF 0.0015339807878856412f  // 2*pi / LUT_SIZE
#define INV_SCALE (1.0f / 11.313708498984761f)  // 1/sqrt(2*dh)

// workspace layout, in floats (ws is ~1 GiB per the harness fill size)
#define OFF_P     0          // P[NC][NB][NH][ND] f32 = 8388608 floats (33.5 MB)
#define OFF_ZPART 8388608    // [NC][NB][NH] = 8192
#define OFF_INVZ  8396800    // [NB*NH] = 256

// fused scores + unnormalized per-head context, single pass over cached
__global__ __launch_bounds__(256) void k_fused(const float* __restrict__ cached,
                                               const float* __restrict__ x,
                                               const float* __restrict__ t,
                                               const float* __restrict__ wq,
                                               const float* __restrict__ bq,
                                               const float* __restrict__ wk,
                                               const float* __restrict__ bk,
                                               float* __restrict__ ws) {
    __shared__ float se[2][RG][16];    // e broadcast, double-buffered (1 KB)
    int tid = threadIdx.x;
    int b = blockIdx.x >> 5;           // / NC
    int c = blockIdx.x & (NC - 1);
    int s0 = c * SC;
    int m = tid * 4;

    // key params with LUT scale folded in: idx = rint(v*krK + kbK)
    float4 wkv = *(const float4*)(wk + m);
    float4 kbv = *(const float4*)(bk + m);
    float4 krK, kbK;
    krK.x = KF / (1.0f + fabsf(wkv.x));
    krK.y = KF / (1.0f + fabsf(wkv.y));
    krK.z = KF / (1.0f + fabsf(wkv.z));
    krK.w = KF / (1.0f + fabsf(wkv.w));
    kbK.x = kbv.x * KF;
    kbK.y = kbv.y * KF;
    kbK.z = kbv.z * KF;
    kbK.w = kbv.w * KF;

    // quantized query phase (radians, pre-negated)
    float tphi = t[b] * PHIF;
    float4 xv = *(const float4*)(x + b * ND + m);
    float4 wqv = *(const float4*)(wq + m);
    float4 bqv = *(const float4*)(bq + m);
    float jq0 = -rintf((xv.x / (1.0f + fabsf(wqv.x)) + bqv.x + tphi) * KF) * ANGF;
    float jq1 = -rintf((xv.y / (1.0f + fabsf(wqv.y)) + bqv.y + tphi) * KF) * ANGF;
    float jq2 = -rintf((xv.z / (1.0f + fabsf(wqv.z)) + bqv.z + tphi) * KF) * ANGF;
    float jq3 = -rintf((xv.w / (1.0f + fabsf(wqv.w)) + bqv.w + tphi) * KF) * ANGF;

    float4 acch[16];
    #pragma unroll
    for (int h = 0; h < 16; ++h) acch[h] = make_float4(0.f, 0.f, 0.f, 0.f);
    float zacc = 0.f;

    const float* base = cached + ((size_t)b * NS + s0) * ND + m;

    for (int g = 0; g < SC / RG; ++g) {
        float4 v[RG];
        #pragma unroll
        for (int r = 0; r < RG; ++r)
            v[r] = *(const float4*)(base + (size_t)(g * RG + r) * ND);

        float ev[RG];
        #pragma unroll
        for (int r = 0; r < RG; ++r) {
            // cos(theta_k_hat - theta_q_hat) == cos_k*cos_q + sin_k*sin_q exactly
            float a0 = fmaf(rintf(fmaf(v[r].x, krK.x, kbK.x)), ANGF, jq0);
            float a1 = fmaf(rintf(fmaf(v[r].y, krK.y, kbK.y)), ANGF, jq1);
            float a2 = fmaf(rintf(fmaf(v[r].z, krK.z, kbK.z)), ANGF, jq2);
            float a3 = fmaf(rintf(fmaf(v[r].w, krK.w, kbK.w)), ANGF, jq3);
            float p = (__cosf(a0) + __cosf(a1)) + (__cosf(a2) + __cosf(a3));
            p += __shfl_xor(p, 1, 16);
            p += __shfl_xor(p, 2, 16);
            p += __shfl_xor(p, 4, 16);
            p += __shfl_xor(p, 8, 16);
            ev[r] = __expf(p * INV_SCALE);   // no-max softmax: |score| <= 5.66
        }
        int buf = g & 1;
        if ((tid & 15) == 0) {
            #pragma unroll
            for (int r = 0; r < RG; ++r) se[buf][r][tid >> 4] = ev[r];
        }
        #pragma unroll
        for (int r = 0; r < RG; ++r) zacc += ev[r];
        __syncthreads();   // dbuf => one sync/group covers both hazards
        #pragma unroll
        for (int r = 0; r < RG; ++r) {
            const float4* s4 = (const float4*)se[buf][r];
            float4 ea = s4[0], eb = s4[1], ec = s4[2], ed = s4[3];
            float4 vv = v[r];
#define ACC4(i, e) acch[i].x = fmaf(e, vv.x, acch[i].x); \
                   acch[i].y = fmaf(e, vv.y, acch[i].y); \
                   acch[i].z = fmaf(e, vv.z, acch[i].z); \
                   acch[i].w = fmaf(e, vv.w, acch[i].w);
            ACC4(0, ea.x)  ACC4(1, ea.y)  ACC4(2, ea.z)  ACC4(3, ea.w)
            ACC4(4, eb.x)  ACC4(5, eb.y)  ACC4(6, eb.z)  ACC4(7, eb.w)
            ACC4(8, ec.x)  ACC4(9, ec.y)  ACC4(10, ec.z) ACC4(11, ec.w)
            ACC4(12, ed.x) ACC4(13, ed.y) ACC4(14, ed.z) ACC4(15, ed.w)
#undef ACC4
        }
    }

    // write per-head context partials, coalesced per h
    float* P = ws + OFF_P + (size_t)(c * NB + b) * (NH * ND) + m;
    #pragma unroll
    for (int h = 0; h < 16; ++h)
        *(float4*)(P + h * ND) = acch[h];
    if ((tid & 15) == 0)
        ws[OFF_ZPART + (c * NB + b) * NH + (tid >> 4)] = zacc;
}

__global__ __launch_bounds__(256) void k_z(float* __restrict__ ws) {
    int i = threadIdx.x;   // b*NH + h
    float s = 0.f;
    #pragma unroll
    for (int c = 0; c < NC; ++c) s += ws[OFF_ZPART + c * 256 + i];
    ws[OFF_INVZ + i] = 1.0f / s;
}

__global__ __launch_bounds__(256) void k_out(const float* __restrict__ t,
                                             const float* __restrict__ wo,
                                             const float* __restrict__ bo,
                                             const float* __restrict__ osc,
                                             const float* __restrict__ ws,
                                             float* __restrict__ out) {
    __shared__ float red[4][64];
    int bid = blockIdx.x;          // NB*16 = 256
    int b = bid >> 4, mc = bid & 15;
    int tid = threadIdx.x;
    int cq = tid >> 6, ml = tid & 63;
    int m = mc * 64 + ml;
    const float* P = ws + OFF_P;
    float ctx = 0.f;
    #pragma unroll
    for (int h = 0; h < NH; ++h) {
        float s = 0.f;
        #pragma unroll
        for (int i = 0; i < NC / 4; ++i) {
            int c = cq * (NC / 4) + i;
            s += P[(size_t)(c * NB + b) * (NH * ND) + h * ND + m];
        }
        ctx = fmaf(s, ws[OFF_INVZ + b * NH + h], ctx);
    }
    red[cq][ml] = ctx;
    __syncthreads();
    if (cq == 0) {
        ctx = ((red[0][ml] + red[1][ml]) + (red[2][ml] + red[3][ml]));
        float theta = ctx / (1.0f + fabsf(wo[m])) + bo[m] + t[b] * PHIF;
        int idx = ((int)rintf(theta * KF)) & (LUTN - 1);
        float ang = (float)idx * ANGF;
        // precise libm trig: bit-matches the np table entries
        out[b * ND + m] = osc[m] * (cosf(ang) + sinf(ang));
    }
}

extern "C" void kernel_launch(void* const* d_in, const int* in_sizes, int n_in,
                              void* d_out, int out_size, void* d_ws, size_t ws_size,
                              hipStream_t stream) {
    const float* x      = (const float*)d_in[0];
    const float* cached = (const float*)d_in[1];
    const float* t      = (const float*)d_in[2];
    const float* wq     = (const float*)d_in[3];
    const float* bq     = (const float*)d_in[4];
    const float* wk     = (const float*)d_in[5];
    const float* bk     = (const float*)d_in[6];
    const float* wo     = (const float*)d_in[7];
    const float* bo     = (const float*)d_in[8];
    const float* osc    = (const float*)d_in[9];
    float* ws  = (float*)d_ws;
    float* out = (float*)d_out;

    k_fused<<<NB * NC, 256, 0, stream>>>(cached, x, t, wq, bq, wk, bk, ws);
    k_z<<<1, 256, 0, stream>>>(ws);
    k_out<<<NB * (ND / 64), 256, 0, stream>>>(t, wo, bo, osc, ws, out);
}